// Round 5
// baseline (892.354 us; speedup 1.0000x reference)
//
#include <hip/hip_runtime.h>

#define N_NODES 100000
#define E_EDGES 800000
#define E_TOT   900000
#define F 512

typedef __attribute__((ext_vector_type(8))) short short8;
typedef __attribute__((ext_vector_type(4))) float f32x4;
typedef unsigned int u32;

__device__ __forceinline__ float bfu(unsigned int u) {
    union { unsigned int i; float f; } c; c.i = u << 16; return c.f;
}
__device__ __forceinline__ unsigned short f2b(float f) {
    union { float f; unsigned int u; } c; c.f = f;
    return (unsigned short)((c.u + 0x7fffu + ((c.u >> 16) & 1u)) >> 16);
}
__device__ __forceinline__ void gload_lds16(const void* g, void* l) {
    __builtin_amdgcn_global_load_lds(
        (const __attribute__((address_space(1))) u32*)g,
        (__attribute__((address_space(3))) u32*)l, 16, 0, 0);
}

// ---- CSR build ----
__global__ void k_init(unsigned int* deg, unsigned int* counter) {
    int i = blockIdx.x * 256 + threadIdx.x;
    if (i < N_NODES) deg[i] = 1u;           // self loop
    if (i == 0) *counter = 0u;
}

__global__ void k_hist(const int* __restrict__ ei, unsigned int* deg) {
    int e = blockIdx.x * 256 + threadIdx.x;
    if (e < E_EDGES) atomicAdd(&deg[ei[E_EDGES + e]], 1u);
}

__global__ void k_dis(const unsigned int* __restrict__ deg, float* __restrict__ dis) {
    int i = blockIdx.x * 256 + threadIdx.x;
    if (i < N_NODES) dis[i] = rsqrtf((float)deg[i]);
}

__global__ void k_alloc(const unsigned int* __restrict__ deg, unsigned int* counter,
                        int* __restrict__ rs, unsigned int* __restrict__ cursor) {
    int i = blockIdx.x * 256 + threadIdx.x;
    if (i < N_NODES) {
        unsigned int p = atomicAdd(counter, deg[i]);
        rs[i] = (int)p;
        cursor[i] = p;
    }
}

__global__ void k_scatter(const int* __restrict__ ei, const float* __restrict__ dis,
                          unsigned int* __restrict__ cursor,
                          int* __restrict__ col, float* __restrict__ val) {
    int e = blockIdx.x * 256 + threadIdx.x;
    if (e < E_TOT) {
        int s, d;
        if (e < E_EDGES) { s = ei[e]; d = ei[E_EDGES + e]; }
        else             { s = e - E_EDGES; d = s; }
        unsigned int p = atomicAdd(&cursor[d], 1u);
        col[p] = s;
        val[p] = dis[s] * dis[d];
    }
}

// ---- dtype converts ----
__global__ void k_cvtX(const float* __restrict__ xin, unsigned short* __restrict__ xb) {
    int i = blockIdx.x * 256 + threadIdx.x;   // exactly N*F/8 threads
    const float4* p = (const float4*)xin + (size_t)i * 2;
    float4 a = p[0], b = p[1];
    uint4 o;
    o.x = (unsigned)f2b(a.x) | ((unsigned)f2b(a.y) << 16);
    o.y = (unsigned)f2b(a.z) | ((unsigned)f2b(a.w) << 16);
    o.z = (unsigned)f2b(b.x) | ((unsigned)f2b(b.y) << 16);
    o.w = (unsigned)f2b(b.z) | ((unsigned)f2b(b.w) << 16);
    *(uint4*)(xb + (size_t)i * 8) = o;
}

__global__ void k_cvtW(const float* __restrict__ W, unsigned short* __restrict__ Wt) {
    int t = blockIdx.x * 256 + threadIdx.x;   // F*F threads
    if (t < F * F) {
        int n = t >> 9, k = t & 511;
        Wt[t] = f2b(W[k * F + n]);            // Wt[n][k] = W[k][n]
    }
}

// ---- GEMM (2-phase double-buffered): out = A[M,512] x Bt[512,512]^T + bias ----
// bf16 in, f32 acc; epilogue: +bias, optional relu; bf16 or f32(nontemporal) out.
__global__ __launch_bounds__(256)
void gemm_bt(const unsigned short* __restrict__ A, const unsigned short* __restrict__ Bt,
             const float* __restrict__ bias,
             unsigned short* __restrict__ outb, float* __restrict__ outf,
             int relu, int M) {
    __shared__ unsigned short lsa[2][128 * 64];
    __shared__ unsigned short lsb[2][128 * 64];
    int bx = blockIdx.x;        // M tile
    int by = blockIdx.y;        // N tile (0..3)
    int t  = threadIdx.x;
    int lane = t & 63, w = t >> 6;
    int wr = w >> 1, wc = w & 1;

    f32x4 acc[4][4];
    #pragma unroll
    for (int m = 0; m < 4; ++m)
        #pragma unroll
        for (int n = 0; n < 4; ++n)
            acc[m][n] = (f32x4){0.f, 0.f, 0.f, 0.f};

    int rowBase = bx * 128;

    // staging coords: slot i covers LDS 16B-chunk (i*256+t)
    int ar[4], akc[4], br[4];
    #pragma unroll
    for (int i = 0; i < 4; ++i) {
        int idx = i * 256 + t;
        int r = idx >> 3;
        akc[i] = (idx & 7) * 8;
        int ga = rowBase + r; if (ga >= M) ga = M - 1;
        ar[i] = ga;
        br[i] = by * 128 + r;
    }

    auto STAGE = [&](int buf, int k0) {
        #pragma unroll
        for (int i = 0; i < 4; ++i) {
            int idx = i * 256 + t;
            gload_lds16(A + (size_t)ar[i] * F + k0 + akc[i], &lsa[buf][idx * 8]);
            gload_lds16(Bt + (size_t)br[i] * F + k0 + akc[i], &lsb[buf][idx * 8]);
        }
    };

    STAGE(0, 0);
    __syncthreads();                       // vmcnt(0) drain + barrier
    #pragma unroll 2
    for (int kt = 0; kt < 8; ++kt) {       // K = 512 = 8 x 64
        int cur = kt & 1;
        if (kt < 7) STAGE(cur ^ 1, (kt + 1) * 64);   // prefetch next tile
        #pragma unroll
        for (int ks = 0; ks < 2; ++ks) {
            int koff = ks * 32 + (lane >> 4) * 8;
            short8 af[4], bfr[4];
            #pragma unroll
            for (int m = 0; m < 4; ++m)
                af[m] = *(short8*)&lsa[cur][(wr * 64 + m * 16 + (lane & 15)) * 64 + koff];
            #pragma unroll
            for (int n = 0; n < 4; ++n)
                bfr[n] = *(short8*)&lsb[cur][(wc * 64 + n * 16 + (lane & 15)) * 64 + koff];
            #pragma unroll
            for (int m = 0; m < 4; ++m)
                #pragma unroll
                for (int n = 0; n < 4; ++n)
                    acc[m][n] = __builtin_amdgcn_mfma_f32_16x16x32_bf16(af[m], bfr[n], acc[m][n], 0, 0, 0);
        }
        __syncthreads();                   // drains prefetch vmcnt + lgkm, then barrier
    }

    int rq = (lane >> 4) * 4, cq = lane & 15;
    #pragma unroll
    for (int m = 0; m < 4; ++m)
        #pragma unroll
        for (int n = 0; n < 4; ++n) {
            int colv = by * 128 + wc * 64 + n * 16 + cq;
            float bv = bias[colv];
            #pragma unroll
            for (int j = 0; j < 4; ++j) {
                int row = rowBase + wr * 64 + m * 16 + rq + j;
                if (row < M) {
                    float v = acc[m][n][j] + bv;
                    if (relu) v = fmaxf(v, 0.f);
                    if (outb) outb[(size_t)row * F + colv] = f2b(v);
                    else __builtin_nontemporal_store(v, outf + (size_t)row * F + colv);
                }
            }
        }
}

// ---- aggregation (column-halved): g[d, half] = sum_e val[e] * hin[col[e], half] ----
// bf16 in, f32 acc, bf16 out. blockIdx.y = column half (256 cols = 51 MB working set).
__global__ __launch_bounds__(256)
void k_agg2(const unsigned short* __restrict__ hin, const int* __restrict__ rs,
            const unsigned int* __restrict__ deg,
            const int* __restrict__ col, const float* __restrict__ val,
            unsigned short* __restrict__ outb) {
    int node = blockIdx.x * 4 + (threadIdx.x >> 6);
    int lane = threadIdx.x & 63;
    int coff = blockIdx.y * 256 + lane * 4;   // 4 bf16 (8 B) per lane
    if (node >= N_NODES) return;
    int e0 = rs[node], e1 = e0 + (int)deg[node];
    float a0 = 0.f, a1 = 0.f, a2 = 0.f, a3 = 0.f;
    const unsigned short* base = hin + coff;
    for (int e = e0; e < e1; ++e) {
        int s = col[e];
        float wv = val[e];
        uint2 v = *(const uint2*)(base + (size_t)s * F);
        a0 += wv * bfu(v.x & 0xffffu);
        a1 += wv * bfu(v.x >> 16);
        a2 += wv * bfu(v.y & 0xffffu);
        a3 += wv * bfu(v.y >> 16);
    }
    uint2 o;
    o.x = (unsigned)f2b(a0) | ((unsigned)f2b(a1) << 16);
    o.y = (unsigned)f2b(a2) | ((unsigned)f2b(a3) << 16);
    *(uint2*)(outb + (size_t)node * F + coff) = o;
}

extern "C" void kernel_launch(void* const* d_in, const int* in_sizes, int n_in,
                              void* d_out, int out_size, void* d_ws, size_t ws_size,
                              hipStream_t stream) {
    const float* x  = (const float*)d_in[0];
    const int*   ei = (const int*)d_in[1];
    const float* W1 = (const float*)d_in[2];
    const float* b1 = (const float*)d_in[3];
    const float* W2 = (const float*)d_in[4];
    const float* b2 = (const float*)d_in[5];
    float* out = (float*)d_out;

    char* ws = (char*)d_ws;
    size_t off = 0;
    auto alloc = [&](size_t bytes) -> void* {
        off = (off + 255) & ~(size_t)255;
        void* p = ws + off;
        off += bytes;
        return p;
    };

    unsigned short* tb  = (unsigned short*)alloc((size_t)N_NODES * F * 2); // agg out (bf16)
    unsigned short* W1t = (unsigned short*)alloc((size_t)F * F * 2);
    unsigned short* W2t = (unsigned short*)alloc((size_t)F * F * 2);
    unsigned int*   deg = (unsigned int*)alloc((size_t)N_NODES * 4);
    float*          dis = (float*)alloc((size_t)N_NODES * 4);
    int*            rs  = (int*)alloc((size_t)N_NODES * 4);
    unsigned int*   cur = (unsigned int*)alloc((size_t)N_NODES * 4);
    unsigned int*   cnt = (unsigned int*)alloc(256);
    int*            col = (int*)alloc((size_t)E_TOT * 4);
    float*          val = (float*)alloc((size_t)E_TOT * 4);

    // d_out doubles as scratch: lower half = h1 (bf16), upper half = x (bf16).
    // Both are dead before gemm2 overwrites d_out with the fp32 result.
    unsigned short* h1b = (unsigned short*)d_out;
    unsigned short* xb  = (unsigned short*)((char*)d_out + (size_t)N_NODES * F * 2);

    int nb = (N_NODES + 255) / 256;

    k_init<<<nb, 256, 0, stream>>>(deg, cnt);
    k_hist<<<(E_EDGES + 255) / 256, 256, 0, stream>>>(ei, deg);
    k_dis<<<nb, 256, 0, stream>>>(deg, dis);
    k_alloc<<<nb, 256, 0, stream>>>(deg, cnt, rs, cur);
    k_scatter<<<(E_TOT + 255) / 256, 256, 0, stream>>>(ei, dis, cur, col, val);

    k_cvtW<<<(F * F + 255) / 256, 256, 0, stream>>>(W1, W1t);
    k_cvtW<<<(F * F + 255) / 256, 256, 0, stream>>>(W2, W2t);
    k_cvtX<<<(N_NODES * F / 8) / 256, 256, 0, stream>>>(x, xb);

    dim3 ggrid((N_NODES + 127) / 128, F / 128);
    dim3 agrid((N_NODES + 3) / 4, 2);

    // layer 1: h1 = relu((A x) W1 + b1)   [reassociated]
    k_agg2<<<agrid, 256, 0, stream>>>(xb, rs, deg, col, val, tb);
    gemm_bt<<<ggrid, 256, 0, stream>>>(tb, W1t, b1, h1b, nullptr, 1, N_NODES);

    // layer 2: out = (A h1) W2 + b2       [reassociated]
    k_agg2<<<agrid, 256, 0, stream>>>(h1b, rs, deg, col, val, tb);
    gemm_bt<<<ggrid, 256, 0, stream>>>(tb, W2t, b2, nullptr, out, 0, N_NODES);
}

// Round 6
// 723.871 us; speedup vs baseline: 1.2328x; 1.2328x over previous
//
#include <hip/hip_runtime.h>

#define N_NODES 100000
#define E_EDGES 800000
#define E_TOT   900000
#define F 512

typedef __attribute__((ext_vector_type(8))) short short8;
typedef __attribute__((ext_vector_type(4))) float f32x4;
typedef unsigned int u32;

__device__ __forceinline__ float bfu(unsigned int u) {
    union { unsigned int i; float f; } c; c.i = u << 16; return c.f;
}
__device__ __forceinline__ unsigned short f2b(float f) {
    union { float f; unsigned int u; } c; c.f = f;
    return (unsigned short)((c.u + 0x7fffu + ((c.u >> 16) & 1u)) >> 16);
}
__device__ __forceinline__ float fbits(unsigned int u) {
    union { unsigned int i; float f; } c; c.i = u; return c.f;
}
__device__ __forceinline__ unsigned int bits(float f) {
    union { float f; unsigned int i; } c; c.f = f; return c.i;
}
__device__ __forceinline__ void gload_lds16(const void* g, void* l) {
    __builtin_amdgcn_global_load_lds(
        (const __attribute__((address_space(1))) u32*)g,
        (__attribute__((address_space(3))) u32*)l, 16, 0, 0);
}

// ---- CSR build ----
__global__ void k_init(unsigned int* deg, unsigned int* counter) {
    int i = blockIdx.x * 256 + threadIdx.x;
    if (i < N_NODES) deg[i] = 1u;           // self loop
    if (i == 0) *counter = 0u;
}

__global__ void k_hist(const int* __restrict__ ei, unsigned int* deg) {
    int e = blockIdx.x * 256 + threadIdx.x;
    if (e < E_EDGES) atomicAdd(&deg[ei[E_EDGES + e]], 1u);
}

__global__ void k_dis(const unsigned int* __restrict__ deg, float* __restrict__ dis) {
    int i = blockIdx.x * 256 + threadIdx.x;
    if (i < N_NODES) dis[i] = rsqrtf((float)deg[i]);
}

__global__ void k_alloc(const unsigned int* __restrict__ deg, unsigned int* counter,
                        int2* __restrict__ seg, unsigned int* __restrict__ cursor) {
    int i = blockIdx.x * 256 + threadIdx.x;
    if (i < N_NODES) {
        unsigned int d = deg[i];
        unsigned int p = atomicAdd(counter, d);
        seg[i] = make_int2((int)p, (int)(p + d));
        cursor[i] = p;
    }
}

__global__ void k_scatter(const int* __restrict__ ei, const float* __restrict__ dis,
                          unsigned int* __restrict__ cursor,
                          uint2* __restrict__ ev) {
    int e = blockIdx.x * 256 + threadIdx.x;
    if (e < E_TOT) {
        int s, d;
        if (e < E_EDGES) { s = ei[e]; d = ei[E_EDGES + e]; }
        else             { s = e - E_EDGES; d = s; }
        unsigned int p = atomicAdd(&cursor[d], 1u);
        ev[p] = make_uint2((unsigned)s, bits(dis[s] * dis[d]));
    }
}

// ---- dtype converts ----
__global__ void k_cvtX(const float* __restrict__ xin, unsigned short* __restrict__ xb) {
    int i = blockIdx.x * 256 + threadIdx.x;   // exactly N*F/8 threads
    const float4* p = (const float4*)xin + (size_t)i * 2;
    float4 a = p[0], b = p[1];
    uint4 o;
    o.x = (unsigned)f2b(a.x) | ((unsigned)f2b(a.y) << 16);
    o.y = (unsigned)f2b(a.z) | ((unsigned)f2b(a.w) << 16);
    o.z = (unsigned)f2b(b.x) | ((unsigned)f2b(b.y) << 16);
    o.w = (unsigned)f2b(b.z) | ((unsigned)f2b(b.w) << 16);
    *(uint4*)(xb + (size_t)i * 8) = o;
}

__global__ void k_cvtW(const float* __restrict__ W, unsigned short* __restrict__ Wt) {
    int t = blockIdx.x * 256 + threadIdx.x;   // F*F threads
    if (t < F * F) {
        int n = t >> 9, k = t & 511;
        Wt[t] = f2b(W[k * F + n]);            // Wt[n][k] = W[k][n]
    }
}

// ---- GEMM (m97 single-buffer): out = A[M,512] x Bt[512,512]^T + bias ----
// bf16 in, f32 acc; epilogue: +bias, optional relu; bf16 or f32(nontemporal) out.
__global__ __launch_bounds__(256)
void gemm_bt(const unsigned short* __restrict__ A, const unsigned short* __restrict__ Bt,
             const float* __restrict__ bias,
             unsigned short* __restrict__ outb, float* __restrict__ outf,
             int relu, int M) {
    __shared__ unsigned short lsa[128 * 64];
    __shared__ unsigned short lsb[128 * 64];
    int bx = blockIdx.x;        // M tile
    int by = blockIdx.y;        // N tile (0..3)
    int t  = threadIdx.x;
    int lane = t & 63, w = t >> 6;
    int wr = w >> 1, wc = w & 1;

    f32x4 acc[4][4];
    #pragma unroll
    for (int m = 0; m < 4; ++m)
        #pragma unroll
        for (int n = 0; n < 4; ++n)
            acc[m][n] = (f32x4){0.f, 0.f, 0.f, 0.f};

    int rowBase = bx * 128;

    // staging coords: slot i covers LDS 16B-chunk (i*256+t)
    int ar[4], akc[4], br[4];
    #pragma unroll
    for (int i = 0; i < 4; ++i) {
        int idx = i * 256 + t;
        int r = idx >> 3;
        akc[i] = (idx & 7) * 8;
        int ga = rowBase + r; if (ga >= M) ga = M - 1;
        ar[i] = ga;
        br[i] = by * 128 + r;
    }

    for (int k0 = 0; k0 < F; k0 += 64) {
        #pragma unroll
        for (int i = 0; i < 4; ++i) {
            int idx = i * 256 + t;
            gload_lds16(A + (size_t)ar[i] * F + k0 + akc[i], lsa + idx * 8);
            gload_lds16(Bt + (size_t)br[i] * F + k0 + akc[i], lsb + idx * 8);
        }
        __syncthreads();
        #pragma unroll
        for (int ks = 0; ks < 2; ++ks) {
            int koff = ks * 32 + (lane >> 4) * 8;
            short8 af[4], bfr[4];
            #pragma unroll
            for (int m = 0; m < 4; ++m)
                af[m] = *(short8*)&lsa[(wr * 64 + m * 16 + (lane & 15)) * 64 + koff];
            #pragma unroll
            for (int n = 0; n < 4; ++n)
                bfr[n] = *(short8*)&lsb[(wc * 64 + n * 16 + (lane & 15)) * 64 + koff];
            #pragma unroll
            for (int m = 0; m < 4; ++m)
                #pragma unroll
                for (int n = 0; n < 4; ++n)
                    acc[m][n] = __builtin_amdgcn_mfma_f32_16x16x32_bf16(af[m], bfr[n], acc[m][n], 0, 0, 0);
        }
        __syncthreads();
    }

    int rq = (lane >> 4) * 4, cq = lane & 15;
    #pragma unroll
    for (int m = 0; m < 4; ++m)
        #pragma unroll
        for (int n = 0; n < 4; ++n) {
            int colv = by * 128 + wc * 64 + n * 16 + cq;
            float bv = bias[colv];
            #pragma unroll
            for (int j = 0; j < 4; ++j) {
                int row = rowBase + wr * 64 + m * 16 + rq + j;
                if (row < M) {
                    float v = acc[m][n][j] + bv;
                    if (relu) v = fmaxf(v, 0.f);
                    if (outb) outb[(size_t)row * F + colv] = f2b(v);
                    else __builtin_nontemporal_store(v, outf + (size_t)row * F + colv);
                }
            }
        }
}

// ---- aggregation: g[d] = sum_e val[e] * hin[col[e]]  (full 512-wide, x4 unroll) ----
// One wave per node; 16B/lane gathers; 4 independent row-gathers in flight.
__global__ __launch_bounds__(256)
void k_agg(const unsigned short* __restrict__ hin, const int2* __restrict__ seg,
           const uint2* __restrict__ ev,
           unsigned short* __restrict__ outb) {
    int node = blockIdx.x * 4 + (threadIdx.x >> 6);
    int lane = threadIdx.x & 63;
    if (node >= N_NODES) return;
    int2 se = seg[node];
    int e0 = se.x, e1 = se.y;
    float acc[8] = {0, 0, 0, 0, 0, 0, 0, 0};
    const unsigned short* base = hin + lane * 8;

    int e = e0;
    for (; e + 3 < e1; e += 4) {
        uint2 p0 = ev[e], p1 = ev[e + 1], p2 = ev[e + 2], p3 = ev[e + 3];
        uint4 v0 = *(const uint4*)(base + ((size_t)p0.x << 9));
        uint4 v1 = *(const uint4*)(base + ((size_t)p1.x << 9));
        uint4 v2 = *(const uint4*)(base + ((size_t)p2.x << 9));
        uint4 v3 = *(const uint4*)(base + ((size_t)p3.x << 9));
        float w0 = fbits(p0.y), w1 = fbits(p1.y), w2 = fbits(p2.y), w3 = fbits(p3.y);
        acc[0] += w0 * bfu(v0.x & 0xffffu); acc[1] += w0 * bfu(v0.x >> 16);
        acc[2] += w0 * bfu(v0.y & 0xffffu); acc[3] += w0 * bfu(v0.y >> 16);
        acc[4] += w0 * bfu(v0.z & 0xffffu); acc[5] += w0 * bfu(v0.z >> 16);
        acc[6] += w0 * bfu(v0.w & 0xffffu); acc[7] += w0 * bfu(v0.w >> 16);
        acc[0] += w1 * bfu(v1.x & 0xffffu); acc[1] += w1 * bfu(v1.x >> 16);
        acc[2] += w1 * bfu(v1.y & 0xffffu); acc[3] += w1 * bfu(v1.y >> 16);
        acc[4] += w1 * bfu(v1.z & 0xffffu); acc[5] += w1 * bfu(v1.z >> 16);
        acc[6] += w1 * bfu(v1.w & 0xffffu); acc[7] += w1 * bfu(v1.w >> 16);
        acc[0] += w2 * bfu(v2.x & 0xffffu); acc[1] += w2 * bfu(v2.x >> 16);
        acc[2] += w2 * bfu(v2.y & 0xffffu); acc[3] += w2 * bfu(v2.y >> 16);
        acc[4] += w2 * bfu(v2.z & 0xffffu); acc[5] += w2 * bfu(v2.z >> 16);
        acc[6] += w2 * bfu(v2.w & 0xffffu); acc[7] += w2 * bfu(v2.w >> 16);
        acc[0] += w3 * bfu(v3.x & 0xffffu); acc[1] += w3 * bfu(v3.x >> 16);
        acc[2] += w3 * bfu(v3.y & 0xffffu); acc[3] += w3 * bfu(v3.y >> 16);
        acc[4] += w3 * bfu(v3.z & 0xffffu); acc[5] += w3 * bfu(v3.z >> 16);
        acc[6] += w3 * bfu(v3.w & 0xffffu); acc[7] += w3 * bfu(v3.w >> 16);
    }
    for (; e < e1; ++e) {
        uint2 p = ev[e];
        uint4 v = *(const uint4*)(base + ((size_t)p.x << 9));
        float wv = fbits(p.y);
        acc[0] += wv * bfu(v.x & 0xffffu); acc[1] += wv * bfu(v.x >> 16);
        acc[2] += wv * bfu(v.y & 0xffffu); acc[3] += wv * bfu(v.y >> 16);
        acc[4] += wv * bfu(v.z & 0xffffu); acc[5] += wv * bfu(v.z >> 16);
        acc[6] += wv * bfu(v.w & 0xffffu); acc[7] += wv * bfu(v.w >> 16);
    }

    uint4 o;
    o.x = (unsigned)f2b(acc[0]) | ((unsigned)f2b(acc[1]) << 16);
    o.y = (unsigned)f2b(acc[2]) | ((unsigned)f2b(acc[3]) << 16);
    o.z = (unsigned)f2b(acc[4]) | ((unsigned)f2b(acc[5]) << 16);
    o.w = (unsigned)f2b(acc[6]) | ((unsigned)f2b(acc[7]) << 16);
    *(uint4*)(outb + (size_t)node * F + lane * 8) = o;
}

extern "C" void kernel_launch(void* const* d_in, const int* in_sizes, int n_in,
                              void* d_out, int out_size, void* d_ws, size_t ws_size,
                              hipStream_t stream) {
    const float* x  = (const float*)d_in[0];
    const int*   ei = (const int*)d_in[1];
    const float* W1 = (const float*)d_in[2];
    const float* b1 = (const float*)d_in[3];
    const float* W2 = (const float*)d_in[4];
    const float* b2 = (const float*)d_in[5];
    float* out = (float*)d_out;

    char* ws = (char*)d_ws;
    size_t off = 0;
    auto alloc = [&](size_t bytes) -> void* {
        off = (off + 255) & ~(size_t)255;
        void* p = ws + off;
        off += bytes;
        return p;
    };

    unsigned short* tb  = (unsigned short*)alloc((size_t)N_NODES * F * 2); // agg out (bf16)
    unsigned short* W1t = (unsigned short*)alloc((size_t)F * F * 2);
    unsigned short* W2t = (unsigned short*)alloc((size_t)F * F * 2);
    unsigned int*   deg = (unsigned int*)alloc((size_t)N_NODES * 4);
    float*          dis = (float*)alloc((size_t)N_NODES * 4);
    int2*           seg = (int2*)alloc((size_t)N_NODES * 8);
    unsigned int*   cur = (unsigned int*)alloc((size_t)N_NODES * 4);
    unsigned int*   cnt = (unsigned int*)alloc(256);
    uint2*          ev  = (uint2*)alloc((size_t)E_TOT * 8);

    // d_out doubles as scratch: lower half = h1 (bf16), upper half = x (bf16).
    // Both are dead before gemm2 overwrites d_out with the fp32 result.
    unsigned short* h1b = (unsigned short*)d_out;
    unsigned short* xb  = (unsigned short*)((char*)d_out + (size_t)N_NODES * F * 2);

    int nb = (N_NODES + 255) / 256;

    k_init<<<nb, 256, 0, stream>>>(deg, cnt);
    k_hist<<<(E_EDGES + 255) / 256, 256, 0, stream>>>(ei, deg);
    k_dis<<<nb, 256, 0, stream>>>(deg, dis);
    k_alloc<<<nb, 256, 0, stream>>>(deg, cnt, seg, cur);
    k_scatter<<<(E_TOT + 255) / 256, 256, 0, stream>>>(ei, dis, cur, ev);

    k_cvtW<<<(F * F + 255) / 256, 256, 0, stream>>>(W1, W1t);
    k_cvtW<<<(F * F + 255) / 256, 256, 0, stream>>>(W2, W2t);
    k_cvtX<<<(N_NODES * F / 8) / 256, 256, 0, stream>>>(x, xb);

    dim3 ggrid((N_NODES + 127) / 128, F / 128);

    // layer 1: h1 = relu((A x) W1 + b1)   [reassociated]
    k_agg<<<(N_NODES + 3) / 4, 256, 0, stream>>>(xb, seg, ev, tb);
    gemm_bt<<<ggrid, 256, 0, stream>>>(tb, W1t, b1, h1b, nullptr, 1, N_NODES);

    // layer 2: out = (A h1) W2 + b2       [reassociated]
    k_agg<<<(N_NODES + 3) / 4, 256, 0, stream>>>(h1b, seg, ev, tb);
    gemm_bt<<<ggrid, 256, 0, stream>>>(tb, W2t, b2, nullptr, out, 0, N_NODES);
}

// Round 7
// 685.179 us; speedup vs baseline: 1.3024x; 1.0565x over previous
//
#include <hip/hip_runtime.h>

#define N_NODES 100000
#define E_EDGES 800000
#define E_TOT   900000
#define F 512

typedef __attribute__((ext_vector_type(8))) short short8;
typedef __attribute__((ext_vector_type(4))) float f32x4;
typedef unsigned int u32;

__device__ __forceinline__ float bfu(unsigned int u) {
    union { unsigned int i; float f; } c; c.i = u << 16; return c.f;
}
__device__ __forceinline__ unsigned short f2b(float f) {
    union { float f; unsigned int u; } c; c.f = f;
    return (unsigned short)((c.u + 0x7fffu + ((c.u >> 16) & 1u)) >> 16);
}
__device__ __forceinline__ float fbits(unsigned int u) {
    union { unsigned int i; float f; } c; c.i = u; return c.f;
}
__device__ __forceinline__ unsigned int bits(float f) {
    union { float f; unsigned int i; } c; c.f = f; return c.i;
}
__device__ __forceinline__ void gload_lds16(const void* g, void* l) {
    __builtin_amdgcn_global_load_lds(
        (const __attribute__((address_space(1))) u32*)g,
        (__attribute__((address_space(3))) u32*)l, 16, 0, 0);
}

// ---- CSR build ----
__global__ void k_init(unsigned int* deg, unsigned int* counter) {
    int i = blockIdx.x * 256 + threadIdx.x;
    if (i < N_NODES) deg[i] = 1u;           // self loop
    if (i == 0) *counter = 0u;
}

__global__ void k_hist(const int* __restrict__ ei, unsigned int* deg) {
    int e = blockIdx.x * 256 + threadIdx.x;
    if (e < E_EDGES) atomicAdd(&deg[ei[E_EDGES + e]], 1u);
}

// dis + seg + cursor in one pass over deg
__global__ void k_disalloc(const unsigned int* __restrict__ deg, unsigned int* counter,
                           float* __restrict__ dis,
                           int2* __restrict__ seg, unsigned int* __restrict__ cursor) {
    int i = blockIdx.x * 256 + threadIdx.x;
    if (i < N_NODES) {
        unsigned int d = deg[i];
        dis[i] = rsqrtf((float)d);
        unsigned int p = atomicAdd(counter, d);
        seg[i] = make_int2((int)p, (int)(p + d));
        cursor[i] = p;
    }
}

__global__ void k_scatter(const int* __restrict__ ei, const float* __restrict__ dis,
                          unsigned int* __restrict__ cursor,
                          uint2* __restrict__ ev) {
    int e = blockIdx.x * 256 + threadIdx.x;
    if (e < E_TOT) {
        int s, d;
        if (e < E_EDGES) { s = ei[e]; d = ei[E_EDGES + e]; }
        else             { s = e - E_EDGES; d = s; }
        unsigned int p = atomicAdd(&cursor[d], 1u);
        ev[p] = make_uint2((unsigned)s, bits(dis[s] * dis[d]));
    }
}

// ---- dtype converts ----
__global__ void k_cvtX(const float* __restrict__ xin, unsigned short* __restrict__ xb) {
    int i = blockIdx.x * 256 + threadIdx.x;   // exactly N*F/8 threads
    const f32x4* p = (const f32x4*)xin + (size_t)i * 2;
    f32x4 a = __builtin_nontemporal_load(p);      // x never re-read
    f32x4 b = __builtin_nontemporal_load(p + 1);
    uint4 o;
    o.x = (unsigned)f2b(a[0]) | ((unsigned)f2b(a[1]) << 16);
    o.y = (unsigned)f2b(a[2]) | ((unsigned)f2b(a[3]) << 16);
    o.z = (unsigned)f2b(b[0]) | ((unsigned)f2b(b[1]) << 16);
    o.w = (unsigned)f2b(b[2]) | ((unsigned)f2b(b[3]) << 16);
    *(uint4*)(xb + (size_t)i * 8) = o;
}

// both weights, transposed to Wt[n][k], in one launch
__global__ void k_cvtW(const float* __restrict__ W1, const float* __restrict__ W2,
                       unsigned short* __restrict__ W1t, unsigned short* __restrict__ W2t) {
    int t = blockIdx.x * 256 + threadIdx.x;   // 2*F*F threads
    int which = t >= F * F;
    int u = t - which * F * F;
    int n = u >> 9, k = u & 511;
    const float* W = which ? W2 : W1;
    unsigned short* Wt = which ? W2t : W1t;
    Wt[u] = f2b(W[k * F + n]);
}

// ---- GEMM (BK=32 ping-pong dbuf, 32 KB LDS): out = A[M,512] x Bt^T + bias ----
// bf16 in, f32 acc; epilogue: +bias, optional relu; bf16 or f32(nontemporal) out.
__global__ __launch_bounds__(256)
void gemm_bt(const unsigned short* __restrict__ A, const unsigned short* __restrict__ Bt,
             const float* __restrict__ bias,
             unsigned short* __restrict__ outb, float* __restrict__ outf,
             int relu, int M) {
    __shared__ unsigned short lsa[2][128 * 32];   // 8 KB each
    __shared__ unsigned short lsb[2][128 * 32];
    int bx = blockIdx.x;        // M tile
    int by = blockIdx.y;        // N tile (0..3)
    int t  = threadIdx.x;
    int lane = t & 63, w = t >> 6;
    int wr = w >> 1, wc = w & 1;

    f32x4 acc[4][4];
    #pragma unroll
    for (int m = 0; m < 4; ++m)
        #pragma unroll
        for (int n = 0; n < 4; ++n)
            acc[m][n] = (f32x4){0.f, 0.f, 0.f, 0.f};

    int rowBase = bx * 128;

    // staging coords: chunk idx = i*256+t covers LDS 16B-chunk idx
    // row = idx>>2 (0..127), short-offset kc = (idx&3)*8
    int ar[2], br[2], akc[2];
    #pragma unroll
    for (int i = 0; i < 2; ++i) {
        int idx = i * 256 + t;
        int r = idx >> 2;
        akc[i] = (idx & 3) * 8;
        int ga = rowBase + r; if (ga >= M) ga = M - 1;
        ar[i] = ga;
        br[i] = by * 128 + r;
    }

    auto STAGE = [&](int buf, int k0) {
        #pragma unroll
        for (int i = 0; i < 2; ++i) {
            int idx = i * 256 + t;
            gload_lds16(A + (size_t)ar[i] * F + k0 + akc[i], &lsa[buf][idx * 8]);
            gload_lds16(Bt + (size_t)br[i] * F + k0 + akc[i], &lsb[buf][idx * 8]);
        }
    };
    auto COMPUTE = [&](int buf) {
        int koff = (lane >> 4) * 8;
        int rsel = lane & 15;
        short8 af[4], bfr[4];
        #pragma unroll
        for (int m = 0; m < 4; ++m)
            af[m] = *(short8*)&lsa[buf][(wr * 64 + m * 16 + rsel) * 32 + koff];
        #pragma unroll
        for (int n = 0; n < 4; ++n)
            bfr[n] = *(short8*)&lsb[buf][(wc * 64 + n * 16 + rsel) * 32 + koff];
        #pragma unroll
        for (int m = 0; m < 4; ++m)
            #pragma unroll
            for (int n = 0; n < 4; ++n)
                acc[m][n] = __builtin_amdgcn_mfma_f32_16x16x32_bf16(af[m], bfr[n], acc[m][n], 0, 0, 0);
    };

    // K = 512 = 16 tiles of 32. buf0 holds even tiles, buf1 odd.
    STAGE(0, 0);
    __syncthreads();
    #pragma unroll
    for (int kp = 0; kp < 8; ++kp) {
        STAGE(1, (2 * kp + 1) * 32);              // prefetch odd tile
        COMPUTE(0);                               // compute even tile
        __syncthreads();                          // drain prefetch + swap
        if (kp < 7) STAGE(0, (2 * kp + 2) * 32);  // prefetch next even tile
        COMPUTE(1);                               // compute odd tile
        __syncthreads();
    }

    int rq = (lane >> 4) * 4, cq = lane & 15;
    #pragma unroll
    for (int m = 0; m < 4; ++m)
        #pragma unroll
        for (int n = 0; n < 4; ++n) {
            int colv = by * 128 + wc * 64 + n * 16 + cq;
            float bv = bias[colv];
            #pragma unroll
            for (int j = 0; j < 4; ++j) {
                int row = rowBase + wr * 64 + m * 16 + rq + j;
                if (row < M) {
                    float v = acc[m][n][j] + bv;
                    if (relu) v = fmaxf(v, 0.f);
                    if (outb) outb[(size_t)row * F + colv] = f2b(v);
                    else __builtin_nontemporal_store(v, outf + (size_t)row * F + colv);
                }
            }
        }
}

// ---- aggregation: g[d] = sum_e val[e] * hin[col[e]]  (full 512-wide, x4 unroll) ----
// One wave per node; 16B/lane gathers; 4 independent row-gathers in flight.
__global__ __launch_bounds__(256)
void k_agg(const unsigned short* __restrict__ hin, const int2* __restrict__ seg,
           const uint2* __restrict__ ev,
           unsigned short* __restrict__ outb) {
    int node = blockIdx.x * 4 + (threadIdx.x >> 6);
    int lane = threadIdx.x & 63;
    if (node >= N_NODES) return;
    int2 se = seg[node];
    int e0 = se.x, e1 = se.y;
    float acc[8] = {0, 0, 0, 0, 0, 0, 0, 0};
    const unsigned short* base = hin + lane * 8;

    int e = e0;
    for (; e + 3 < e1; e += 4) {
        uint2 p0 = ev[e], p1 = ev[e + 1], p2 = ev[e + 2], p3 = ev[e + 3];
        uint4 v0 = *(const uint4*)(base + ((size_t)p0.x << 9));
        uint4 v1 = *(const uint4*)(base + ((size_t)p1.x << 9));
        uint4 v2 = *(const uint4*)(base + ((size_t)p2.x << 9));
        uint4 v3 = *(const uint4*)(base + ((size_t)p3.x << 9));
        float w0 = fbits(p0.y), w1 = fbits(p1.y), w2 = fbits(p2.y), w3 = fbits(p3.y);
        acc[0] += w0 * bfu(v0.x & 0xffffu); acc[1] += w0 * bfu(v0.x >> 16);
        acc[2] += w0 * bfu(v0.y & 0xffffu); acc[3] += w0 * bfu(v0.y >> 16);
        acc[4] += w0 * bfu(v0.z & 0xffffu); acc[5] += w0 * bfu(v0.z >> 16);
        acc[6] += w0 * bfu(v0.w & 0xffffu); acc[7] += w0 * bfu(v0.w >> 16);
        acc[0] += w1 * bfu(v1.x & 0xffffu); acc[1] += w1 * bfu(v1.x >> 16);
        acc[2] += w1 * bfu(v1.y & 0xffffu); acc[3] += w1 * bfu(v1.y >> 16);
        acc[4] += w1 * bfu(v1.z & 0xffffu); acc[5] += w1 * bfu(v1.z >> 16);
        acc[6] += w1 * bfu(v1.w & 0xffffu); acc[7] += w1 * bfu(v1.w >> 16);
        acc[0] += w2 * bfu(v2.x & 0xffffu); acc[1] += w2 * bfu(v2.x >> 16);
        acc[2] += w2 * bfu(v2.y & 0xffffu); acc[3] += w2 * bfu(v2.y >> 16);
        acc[4] += w2 * bfu(v2.z & 0xffffu); acc[5] += w2 * bfu(v2.z >> 16);
        acc[6] += w2 * bfu(v2.w & 0xffffu); acc[7] += w2 * bfu(v2.w >> 16);
        acc[0] += w3 * bfu(v3.x & 0xffffu); acc[1] += w3 * bfu(v3.x >> 16);
        acc[2] += w3 * bfu(v3.y & 0xffffu); acc[3] += w3 * bfu(v3.y >> 16);
        acc[4] += w3 * bfu(v3.z & 0xffffu); acc[5] += w3 * bfu(v3.z >> 16);
        acc[6] += w3 * bfu(v3.w & 0xffffu); acc[7] += w3 * bfu(v3.w >> 16);
    }
    for (; e < e1; ++e) {
        uint2 p = ev[e];
        uint4 v = *(const uint4*)(base + ((size_t)p.x << 9));
        float wv = fbits(p.y);
        acc[0] += wv * bfu(v.x & 0xffffu); acc[1] += wv * bfu(v.x >> 16);
        acc[2] += wv * bfu(v.y & 0xffffu); acc[3] += wv * bfu(v.y >> 16);
        acc[4] += wv * bfu(v.z & 0xffffu); acc[5] += wv * bfu(v.z >> 16);
        acc[6] += wv * bfu(v.w & 0xffffu); acc[7] += wv * bfu(v.w >> 16);
    }

    uint4 o;
    o.x = (unsigned)f2b(acc[0]) | ((unsigned)f2b(acc[1]) << 16);
    o.y = (unsigned)f2b(acc[2]) | ((unsigned)f2b(acc[3]) << 16);
    o.z = (unsigned)f2b(acc[4]) | ((unsigned)f2b(acc[5]) << 16);
    o.w = (unsigned)f2b(acc[6]) | ((unsigned)f2b(acc[7]) << 16);
    *(uint4*)(outb + (size_t)node * F + lane * 8) = o;
}

extern "C" void kernel_launch(void* const* d_in, const int* in_sizes, int n_in,
                              void* d_out, int out_size, void* d_ws, size_t ws_size,
                              hipStream_t stream) {
    const float* x  = (const float*)d_in[0];
    const int*   ei = (const int*)d_in[1];
    const float* W1 = (const float*)d_in[2];
    const float* b1 = (const float*)d_in[3];
    const float* W2 = (const float*)d_in[4];
    const float* b2 = (const float*)d_in[5];
    float* out = (float*)d_out;

    char* ws = (char*)d_ws;
    size_t off = 0;
    auto alloc = [&](size_t bytes) -> void* {
        off = (off + 255) & ~(size_t)255;
        void* p = ws + off;
        off += bytes;
        return p;
    };

    unsigned short* tb  = (unsigned short*)alloc((size_t)N_NODES * F * 2); // agg out (bf16)
    unsigned short* W1t = (unsigned short*)alloc((size_t)F * F * 2);
    unsigned short* W2t = (unsigned short*)alloc((size_t)F * F * 2);
    unsigned int*   deg = (unsigned int*)alloc((size_t)N_NODES * 4);
    float*          dis = (float*)alloc((size_t)N_NODES * 4);
    int2*           seg = (int2*)alloc((size_t)N_NODES * 8);
    unsigned int*   cur = (unsigned int*)alloc((size_t)N_NODES * 4);
    unsigned int*   cnt = (unsigned int*)alloc(256);
    uint2*          ev  = (uint2*)alloc((size_t)E_TOT * 8);

    // d_out doubles as scratch: lower half = h1 (bf16), upper half = x (bf16).
    // Both are dead before gemm2 overwrites d_out with the fp32 result.
    unsigned short* h1b = (unsigned short*)d_out;
    unsigned short* xb  = (unsigned short*)((char*)d_out + (size_t)N_NODES * F * 2);

    int nb = (N_NODES + 255) / 256;

    k_init<<<nb, 256, 0, stream>>>(deg, cnt);
    k_hist<<<(E_EDGES + 255) / 256, 256, 0, stream>>>(ei, deg);
    k_disalloc<<<nb, 256, 0, stream>>>(deg, cnt, dis, seg, cur);
    k_scatter<<<(E_TOT + 255) / 256, 256, 0, stream>>>(ei, dis, cur, ev);

    k_cvtW<<<(2 * F * F) / 256, 256, 0, stream>>>(W1, W2, W1t, W2t);
    k_cvtX<<<(N_NODES * F / 8) / 256, 256, 0, stream>>>(x, xb);

    dim3 ggrid((N_NODES + 127) / 128, F / 128);

    // layer 1: h1 = relu((A x) W1 + b1)   [reassociated]
    k_agg<<<(N_NODES + 3) / 4, 256, 0, stream>>>(xb, seg, ev, tb);
    gemm_bt<<<ggrid, 256, 0, stream>>>(tb, W1t, b1, h1b, nullptr, 1, N_NODES);

    // layer 2: out = (A h1) W2 + b2       [reassociated]
    k_agg<<<(N_NODES + 3) / 4, 256, 0, stream>>>(h1b, seg, ev, tb);
    gemm_bt<<<ggrid, 256, 0, stream>>>(tb, W2t, b2, nullptr, out, 0, N_NODES);
}

// Round 8
// 647.294 us; speedup vs baseline: 1.3786x; 1.0585x over previous
//
#include <hip/hip_runtime.h>

#define N_NODES 100000
#define E_EDGES 800000
#define E_TOT   900000
#define F 512

typedef __attribute__((ext_vector_type(8))) short short8;
typedef __attribute__((ext_vector_type(4))) float f32x4;
typedef unsigned int u32;

__device__ __forceinline__ float bfu(unsigned int u) {
    union { unsigned int i; float f; } c; c.i = u << 16; return c.f;
}
__device__ __forceinline__ unsigned short f2b(float f) {
    union { float f; unsigned int u; } c; c.f = f;
    return (unsigned short)((c.u + 0x7fffu + ((c.u >> 16) & 1u)) >> 16);
}
__device__ __forceinline__ float fbits(unsigned int u) {
    union { unsigned int i; float f; } c; c.i = u; return c.f;
}
__device__ __forceinline__ unsigned int bits(float f) {
    union { float f; unsigned int i; } c; c.f = f; return c.i;
}
__device__ __forceinline__ void gload_lds16(const void* g, void* l) {
    __builtin_amdgcn_global_load_lds(
        (const __attribute__((address_space(1))) u32*)g,
        (__attribute__((address_space(3))) u32*)l, 16, 0, 0);
}

// ---- CSR build ----
__global__ void k_init(unsigned int* deg, unsigned int* counter) {
    int i = blockIdx.x * 256 + threadIdx.x;
    if (i < N_NODES) deg[i] = 1u;           // self loop
    if (i == 0) *counter = 0u;
}

__global__ void k_hist(const int* __restrict__ ei, unsigned int* deg) {
    int e = blockIdx.x * 256 + threadIdx.x;
    if (e < E_EDGES) atomicAdd(&deg[ei[E_EDGES + e]], 1u);
}

// dis + seg + cursor in one pass over deg
__global__ void k_disalloc(const unsigned int* __restrict__ deg, unsigned int* counter,
                           float* __restrict__ dis,
                           int2* __restrict__ seg, unsigned int* __restrict__ cursor) {
    int i = blockIdx.x * 256 + threadIdx.x;
    if (i < N_NODES) {
        unsigned int d = deg[i];
        dis[i] = rsqrtf((float)d);
        unsigned int p = atomicAdd(counter, d);
        seg[i] = make_int2((int)p, (int)(p + d));
        cursor[i] = p;
    }
}

__global__ void k_scatter(const int* __restrict__ ei, const float* __restrict__ dis,
                          unsigned int* __restrict__ cursor,
                          uint2* __restrict__ ev) {
    int e = blockIdx.x * 256 + threadIdx.x;
    if (e < E_TOT) {
        int s, d;
        if (e < E_EDGES) { s = ei[e]; d = ei[E_EDGES + e]; }
        else             { s = e - E_EDGES; d = s; }
        unsigned int p = atomicAdd(&cursor[d], 1u);
        ev[p] = make_uint2((unsigned)s, bits(dis[s] * dis[d]));
    }
}

// ---- dtype converts ----
__global__ void k_cvtX(const float* __restrict__ xin, unsigned short* __restrict__ xb) {
    int i = blockIdx.x * 256 + threadIdx.x;   // exactly N*F/8 threads
    const f32x4* p = (const f32x4*)xin + (size_t)i * 2;
    f32x4 a = __builtin_nontemporal_load(p);      // x never re-read
    f32x4 b = __builtin_nontemporal_load(p + 1);
    uint4 o;
    o.x = (unsigned)f2b(a[0]) | ((unsigned)f2b(a[1]) << 16);
    o.y = (unsigned)f2b(a[2]) | ((unsigned)f2b(a[3]) << 16);
    o.z = (unsigned)f2b(b[0]) | ((unsigned)f2b(b[1]) << 16);
    o.w = (unsigned)f2b(b[2]) | ((unsigned)f2b(b[3]) << 16);
    *(uint4*)(xb + (size_t)i * 8) = o;
}

// both weights, transposed to Wt[n][k], in one launch
__global__ void k_cvtW(const float* __restrict__ W1, const float* __restrict__ W2,
                       unsigned short* __restrict__ W1t, unsigned short* __restrict__ W2t) {
    int t = blockIdx.x * 256 + threadIdx.x;   // 2*F*F threads
    int which = t >= F * F;
    int u = t - which * F * F;
    int n = u >> 9, k = u & 511;
    const float* W = which ? W2 : W1;
    unsigned short* Wt = which ? W2t : W1t;
    Wt[u] = f2b(W[k * F + n]);
}

// ---- GEMM 256x256 2-phase dbuf: out = A[M,512] x Bt[512,512]^T + bias ----
// 512 threads = 8 waves (2M x 4N); per-wave 128x64 out; BK=64; LDS 128 KB.
// bf16 out goes through LDS re-stage (coalesced 512B rows); f32 out direct NT.
__global__ __launch_bounds__(512, 2)
void gemm_bt(const unsigned short* __restrict__ A, const unsigned short* __restrict__ Bt,
             const float* __restrict__ bias,
             unsigned short* __restrict__ outb, float* __restrict__ outf,
             int relu, int M) {
    __shared__ unsigned short sm[65536];          // 128 KB
    // layout: A buf0 @0, A buf1 @16384, B buf0 @32768, B buf1 @49152 (shorts)

    // bijective XCD remap (m204): pair (bx, by=0/1) lands on one XCD
    int nwg = gridDim.x * gridDim.y;              // 782
    int orig = blockIdx.y * gridDim.x + blockIdx.x;
    int q = nwg >> 3, r = nwg & 7;
    int xcd = orig & 7, j8 = orig >> 3;
    int wgid = (xcd < r ? xcd * (q + 1) : r * (q + 1) + (xcd - r) * q) + j8;
    int by = wgid & 1;                            // N tile (0..1)
    int bx = wgid >> 1;                           // M tile (0..390)

    int t  = threadIdx.x;
    int lane = t & 63, w = t >> 6;
    int wr = w >> 2, wc = w & 3;
    int rsel = lane & 15, khalf = (lane >> 4) * 8;

    f32x4 acc[8][4];
    #pragma unroll
    for (int m = 0; m < 8; ++m)
        #pragma unroll
        for (int n = 0; n < 4; ++n)
            acc[m][n] = (f32x4){0.f, 0.f, 0.f, 0.f};

    int rowBase = bx * 256;

    // staging coords: chunk idx = i*512+t; row = idx>>3 (0..255), kc = (idx&7)*8
    int ar[4], br[4], kcc[4];
    #pragma unroll
    for (int i = 0; i < 4; ++i) {
        int idx = i * 512 + t;
        int rr = idx >> 3;
        kcc[i] = (idx & 7) * 8;
        int ga = rowBase + rr; if (ga >= M) ga = M - 1;
        ar[i] = ga;
        br[i] = by * 256 + rr;
    }

    auto STAGE = [&](int buf, int k0) {
        #pragma unroll
        for (int i = 0; i < 4; ++i) {
            int idx = i * 512 + t;
            gload_lds16(A + (size_t)ar[i] * F + k0 + kcc[i], sm + buf * 16384 + idx * 8);
            gload_lds16(Bt + (size_t)br[i] * F + k0 + kcc[i], sm + 32768 + buf * 16384 + idx * 8);
        }
    };
    auto COMPUTE = [&](int buf) {
        const unsigned short* la = sm + buf * 16384;
        const unsigned short* lb = sm + 32768 + buf * 16384;
        #pragma unroll
        for (int ks = 0; ks < 2; ++ks) {
            int koff = ks * 32 + khalf;
            short8 af[8], bfr[4];
            #pragma unroll
            for (int m = 0; m < 8; ++m)
                af[m] = *(const short8*)&la[(wr * 128 + m * 16 + rsel) * 64 + koff];
            #pragma unroll
            for (int n = 0; n < 4; ++n)
                bfr[n] = *(const short8*)&lb[(wc * 64 + n * 16 + rsel) * 64 + koff];
            #pragma unroll
            for (int m = 0; m < 8; ++m)
                #pragma unroll
                for (int n = 0; n < 4; ++n)
                    acc[m][n] = __builtin_amdgcn_mfma_f32_16x16x32_bf16(af[m], bfr[n], acc[m][n], 0, 0, 0);
        }
    };

    // K = 512 = 8 tiles of 64; even tiles in buf0, odd in buf1.
    STAGE(0, 0);
    __syncthreads();
    #pragma unroll
    for (int kp = 0; kp < 4; ++kp) {
        STAGE(1, (2 * kp + 1) * 64);              // prefetch odd tile
        COMPUTE(0);                               // compute even tile
        __syncthreads();
        if (kp < 3) STAGE(0, (2 * kp + 2) * 64);  // prefetch next even tile
        COMPUTE(1);                               // compute odd tile
        __syncthreads();
    }

    int rq = (lane >> 4) * 4, cq = lane & 15;
    if (outb) {
        // stage bf16 C-tile (256x256 = 128 KB) in LDS, then coalesced store
        #pragma unroll
        for (int m = 0; m < 8; ++m)
            #pragma unroll
            for (int n = 0; n < 4; ++n) {
                int cl = wc * 64 + n * 16 + cq;
                float bv = bias[by * 256 + cl];
                #pragma unroll
                for (int j = 0; j < 4; ++j) {
                    int rl = wr * 128 + m * 16 + rq + j;
                    float v = acc[m][n][j] + bv;
                    if (relu) v = fmaxf(v, 0.f);
                    sm[rl * 256 + cl] = f2b(v);
                }
            }
        __syncthreads();
        #pragma unroll
        for (int p = 0; p < 16; ++p) {
            int sidx = p * 4096 + t * 8;          // short index
            int row = sidx >> 8;
            int col = sidx & 255;
            int grow = rowBase + row;
            if (grow < M) {
                uint4 v = *(const uint4*)&sm[sidx];
                *(uint4*)&outb[(size_t)grow * F + by * 256 + col] = v;
            }
        }
    } else {
        #pragma unroll
        for (int m = 0; m < 8; ++m)
            #pragma unroll
            for (int n = 0; n < 4; ++n) {
                int colv = by * 256 + wc * 64 + n * 16 + cq;
                float bv = bias[colv];
                #pragma unroll
                for (int j = 0; j < 4; ++j) {
                    int row = rowBase + wr * 128 + m * 16 + rq + j;
                    if (row < M) {
                        float v = acc[m][n][j] + bv;
                        if (relu) v = fmaxf(v, 0.f);
                        __builtin_nontemporal_store(v, outf + (size_t)row * F + colv);
                    }
                }
            }
    }
}

// ---- aggregation: g[d] = sum_e val[e] * hin[col[e]]  (512-wide, x8 unroll) ----
// One wave per node; 16B/lane gathers; 8 independent row-gathers in flight.
__global__ __launch_bounds__(256)
void k_agg(const unsigned short* __restrict__ hin, const int2* __restrict__ seg,
           const uint2* __restrict__ ev,
           unsigned short* __restrict__ outb) {
    int node = blockIdx.x * 4 + (threadIdx.x >> 6);
    int lane = threadIdx.x & 63;
    if (node >= N_NODES) return;
    int2 se = seg[node];
    int e0 = se.x, e1 = se.y;
    float acc[8] = {0, 0, 0, 0, 0, 0, 0, 0};
    const unsigned short* base = hin + lane * 8;

    int e = e0;
    int n8 = e0 + ((e1 - e0) & ~7);
    for (; e < n8; e += 8) {
        uint2 p0 = ev[e],     p1 = ev[e + 1], p2 = ev[e + 2], p3 = ev[e + 3];
        uint2 p4 = ev[e + 4], p5 = ev[e + 5], p6 = ev[e + 6], p7 = ev[e + 7];
        uint4 v0 = *(const uint4*)(base + ((size_t)p0.x << 9));
        uint4 v1 = *(const uint4*)(base + ((size_t)p1.x << 9));
        uint4 v2 = *(const uint4*)(base + ((size_t)p2.x << 9));
        uint4 v3 = *(const uint4*)(base + ((size_t)p3.x << 9));
        uint4 v4 = *(const uint4*)(base + ((size_t)p4.x << 9));
        uint4 v5 = *(const uint4*)(base + ((size_t)p5.x << 9));
        uint4 v6 = *(const uint4*)(base + ((size_t)p6.x << 9));
        uint4 v7 = *(const uint4*)(base + ((size_t)p7.x << 9));
        float w0 = fbits(p0.y), w1 = fbits(p1.y), w2 = fbits(p2.y), w3 = fbits(p3.y);
        float w4 = fbits(p4.y), w5 = fbits(p5.y), w6 = fbits(p6.y), w7 = fbits(p7.y);
        acc[0] += w0 * bfu(v0.x & 0xffffu); acc[1] += w0 * bfu(v0.x >> 16);
        acc[2] += w0 * bfu(v0.y & 0xffffu); acc[3] += w0 * bfu(v0.y >> 16);
        acc[4] += w0 * bfu(v0.z & 0xffffu); acc[5] += w0 * bfu(v0.z >> 16);
        acc[6] += w0 * bfu(v0.w & 0xffffu); acc[7] += w0 * bfu(v0.w >> 16);
        acc[0] += w1 * bfu(v1.x & 0xffffu); acc[1] += w1 * bfu(v1.x >> 16);
        acc[2] += w1 * bfu(v1.y & 0xffffu); acc[3] += w1 * bfu(v1.y >> 16);
        acc[4] += w1 * bfu(v1.z & 0xffffu); acc[5] += w1 * bfu(v1.z >> 16);
        acc[6] += w1 * bfu(v1.w & 0xffffu); acc[7] += w1 * bfu(v1.w >> 16);
        acc[0] += w2 * bfu(v2.x & 0xffffu); acc[1] += w2 * bfu(v2.x >> 16);
        acc[2] += w2 * bfu(v2.y & 0xffffu); acc[3] += w2 * bfu(v2.y >> 16);
        acc[4] += w2 * bfu(v2.z & 0xffffu); acc[5] += w2 * bfu(v2.z >> 16);
        acc[6] += w2 * bfu(v2.w & 0xffffu); acc[7] += w2 * bfu(v2.w >> 16);
        acc[0] += w3 * bfu(v3.x & 0xffffu); acc[1] += w3 * bfu(v3.x >> 16);
        acc[2] += w3 * bfu(v3.y & 0xffffu); acc[3] += w3 * bfu(v3.y >> 16);
        acc[4] += w3 * bfu(v3.z & 0xffffu); acc[5] += w3 * bfu(v3.z >> 16);
        acc[6] += w3 * bfu(v3.w & 0xffffu); acc[7] += w3 * bfu(v3.w >> 16);
        acc[0] += w4 * bfu(v4.x & 0xffffu); acc[1] += w4 * bfu(v4.x >> 16);
        acc[2] += w4 * bfu(v4.y & 0xffffu); acc[3] += w4 * bfu(v4.y >> 16);
        acc[4] += w4 * bfu(v4.z & 0xffffu); acc[5] += w4 * bfu(v4.z >> 16);
        acc[6] += w4 * bfu(v4.w & 0xffffu); acc[7] += w4 * bfu(v4.w >> 16);
        acc[0] += w5 * bfu(v5.x & 0xffffu); acc[1] += w5 * bfu(v5.x >> 16);
        acc[2] += w5 * bfu(v5.y & 0xffffu); acc[3] += w5 * bfu(v5.y >> 16);
        acc[4] += w5 * bfu(v5.z & 0xffffu); acc[5] += w5 * bfu(v5.z >> 16);
        acc[6] += w5 * bfu(v5.w & 0xffffu); acc[7] += w5 * bfu(v5.w >> 16);
        acc[0] += w6 * bfu(v6.x & 0xffffu); acc[1] += w6 * bfu(v6.x >> 16);
        acc[2] += w6 * bfu(v6.y & 0xffffu); acc[3] += w6 * bfu(v6.y >> 16);
        acc[4] += w6 * bfu(v6.z & 0xffffu); acc[5] += w6 * bfu(v6.z >> 16);
        acc[6] += w6 * bfu(v6.w & 0xffffu); acc[7] += w6 * bfu(v6.w >> 16);
        acc[0] += w7 * bfu(v7.x & 0xffffu); acc[1] += w7 * bfu(v7.x >> 16);
        acc[2] += w7 * bfu(v7.y & 0xffffu); acc[3] += w7 * bfu(v7.y >> 16);
        acc[4] += w7 * bfu(v7.z & 0xffffu); acc[5] += w7 * bfu(v7.z >> 16);
        acc[6] += w7 * bfu(v7.w & 0xffffu); acc[7] += w7 * bfu(v7.w >> 16);
    }
    for (; e < e1; ++e) {
        uint2 p = ev[e];
        uint4 v = *(const uint4*)(base + ((size_t)p.x << 9));
        float wv = fbits(p.y);
        acc[0] += wv * bfu(v.x & 0xffffu); acc[1] += wv * bfu(v.x >> 16);
        acc[2] += wv * bfu(v.y & 0xffffu); acc[3] += wv * bfu(v.y >> 16);
        acc[4] += wv * bfu(v.z & 0xffffu); acc[5] += wv * bfu(v.z >> 16);
        acc[6] += wv * bfu(v.w & 0xffffu); acc[7] += wv * bfu(v.w >> 16);
    }

    uint4 o;
    o.x = (unsigned)f2b(acc[0]) | ((unsigned)f2b(acc[1]) << 16);
    o.y = (unsigned)f2b(acc[2]) | ((unsigned)f2b(acc[3]) << 16);
    o.z = (unsigned)f2b(acc[4]) | ((unsigned)f2b(acc[5]) << 16);
    o.w = (unsigned)f2b(acc[6]) | ((unsigned)f2b(acc[7]) << 16);
    *(uint4*)(outb + (size_t)node * F + lane * 8) = o;
}

extern "C" void kernel_launch(void* const* d_in, const int* in_sizes, int n_in,
                              void* d_out, int out_size, void* d_ws, size_t ws_size,
                              hipStream_t stream) {
    const float* x  = (const float*)d_in[0];
    const int*   ei = (const int*)d_in[1];
    const float* W1 = (const float*)d_in[2];
    const float* b1 = (const float*)d_in[3];
    const float* W2 = (const float*)d_in[4];
    const float* b2 = (const float*)d_in[5];
    float* out = (float*)d_out;

    char* ws = (char*)d_ws;
    size_t off = 0;
    auto alloc = [&](size_t bytes) -> void* {
        off = (off + 255) & ~(size_t)255;
        void* p = ws + off;
        off += bytes;
        return p;
    };

    unsigned short* tb  = (unsigned short*)alloc((size_t)N_NODES * F * 2); // agg out (bf16)
    unsigned short* W1t = (unsigned short*)alloc((size_t)F * F * 2);
    unsigned short* W2t = (unsigned short*)alloc((size_t)F * F * 2);
    unsigned int*   deg = (unsigned int*)alloc((size_t)N_NODES * 4);
    float*          dis = (float*)alloc((size_t)N_NODES * 4);
    int2*           seg = (int2*)alloc((size_t)N_NODES * 8);
    unsigned int*   cur = (unsigned int*)alloc((size_t)N_NODES * 4);
    unsigned int*   cnt = (unsigned int*)alloc(256);
    uint2*          ev  = (uint2*)alloc((size_t)E_TOT * 8);

    // d_out doubles as scratch: lower half = h1 (bf16), upper half = x (bf16).
    // Both are dead before gemm2 overwrites d_out with the fp32 result.
    unsigned short* h1b = (unsigned short*)d_out;
    unsigned short* xb  = (unsigned short*)((char*)d_out + (size_t)N_NODES * F * 2);

    int nb = (N_NODES + 255) / 256;

    k_init<<<nb, 256, 0, stream>>>(deg, cnt);
    k_hist<<<(E_EDGES + 255) / 256, 256, 0, stream>>>(ei, deg);
    k_disalloc<<<nb, 256, 0, stream>>>(deg, cnt, dis, seg, cur);
    k_scatter<<<(E_TOT + 255) / 256, 256, 0, stream>>>(ei, dis, cur, ev);

    k_cvtW<<<(2 * F * F) / 256, 256, 0, stream>>>(W1, W2, W1t, W2t);
    k_cvtX<<<(N_NODES * F / 8) / 256, 256, 0, stream>>>(x, xb);

    dim3 ggrid(2, (N_NODES + 255) / 256);   // by fastest: A-slab pairs adjacent

    // layer 1: h1 = relu((A x) W1 + b1)   [reassociated]
    k_agg<<<(N_NODES + 3) / 4, 256, 0, stream>>>(xb, seg, ev, tb);
    gemm_bt<<<ggrid, 512, 0, stream>>>(tb, W1t, b1, h1b, nullptr, 1, N_NODES);

    // layer 2: out = (A h1) W2 + b2       [reassociated]
    k_agg<<<(N_NODES + 3) / 4, 256, 0, stream>>>(h1b, seg, ev, tb);
    gemm_bt<<<ggrid, 512, 0, stream>>>(tb, W2t, b2, nullptr, out, 0, N_NODES);
}

// Round 9
// 639.555 us; speedup vs baseline: 1.3953x; 1.0121x over previous
//
#include <hip/hip_runtime.h>

#define N_NODES 100000
#define E_EDGES 800000
#define E_TOT   900000
#define F 512
#define NCHUNK 4
#define CHUNK_SZ 25000

typedef __attribute__((ext_vector_type(8))) short short8;
typedef __attribute__((ext_vector_type(4))) float f32x4;
typedef unsigned int u32;

__device__ __forceinline__ float bfu(unsigned int u) {
    union { unsigned int i; float f; } c; c.i = u << 16; return c.f;
}
__device__ __forceinline__ unsigned short f2b(float f) {
    union { float f; unsigned int u; } c; c.f = f;
    return (unsigned short)((c.u + 0x7fffu + ((c.u >> 16) & 1u)) >> 16);
}
__device__ __forceinline__ float fbits(unsigned int u) {
    union { unsigned int i; float f; } c; c.i = u; return c.f;
}
__device__ __forceinline__ unsigned int bits(float f) {
    union { float f; unsigned int i; } c; c.f = f; return c.i;
}
__device__ __forceinline__ void gload_lds16(const void* g, void* l) {
    __builtin_amdgcn_global_load_lds(
        (const __attribute__((address_space(1))) u32*)g,
        (__attribute__((address_space(3))) u32*)l, 16, 0, 0);
}

// ---- CSR build (per-(dst, chunk(src)) sub-segments) ----
// deg4 doubles as the scatter cursor array after k_disalloc rewrites it.
__global__ void k_init(uint4* deg4, unsigned int* counter) {
    int i = blockIdx.x * 256 + threadIdx.x;
    if (i < N_NODES) {
        deg4[i] = make_uint4(0u, 0u, 0u, 0u);
        ((unsigned int*)deg4)[i * 4 + i / CHUNK_SZ] = 1u;   // self loop
    }
    if (i == 0) *counter = 0u;
}

__global__ void k_hist(const int* __restrict__ ei, unsigned int* deg4u) {
    int e = blockIdx.x * 256 + threadIdx.x;
    if (e < E_EDGES) {
        int s = ei[e], d = ei[E_EDGES + e];
        atomicAdd(&deg4u[(size_t)d * 4 + s / CHUNK_SZ], 1u);
    }
}

// dis + seg + chunk-starts + cursors in one pass
__global__ void k_disalloc(uint4* deg4, unsigned int* counter,
                           float* __restrict__ dis,
                           int2* __restrict__ seg, int4* __restrict__ cst) {
    int i = blockIdx.x * 256 + threadIdx.x;
    if (i < N_NODES) {
        uint4 d4 = deg4[i];
        unsigned int tot = d4.x + d4.y + d4.z + d4.w;
        dis[i] = rsqrtf((float)tot);
        unsigned int p = atomicAdd(counter, tot);
        int4 cs = make_int4((int)p, (int)(p + d4.x),
                            (int)(p + d4.x + d4.y), (int)(p + d4.x + d4.y + d4.z));
        cst[i] = cs;
        seg[i] = make_int2((int)p, (int)(p + tot));
        deg4[i] = make_uint4((unsigned)cs.x, (unsigned)cs.y,
                             (unsigned)cs.z, (unsigned)cs.w);   // cursors
    }
}

__global__ void k_scatter(const int* __restrict__ ei, const float* __restrict__ dis,
                          unsigned int* __restrict__ cur4,
                          uint2* __restrict__ ev) {
    int e = blockIdx.x * 256 + threadIdx.x;
    if (e < E_TOT) {
        int s, d;
        if (e < E_EDGES) { s = ei[e]; d = ei[E_EDGES + e]; }
        else             { s = e - E_EDGES; d = s; }
        unsigned int p = atomicAdd(&cur4[(size_t)d * 4 + s / CHUNK_SZ], 1u);
        ev[p] = make_uint2((unsigned)s, bits(dis[s] * dis[d]));
    }
}

// ---- dtype converts ----
__global__ void k_cvtX(const float* __restrict__ xin, unsigned short* __restrict__ xb) {
    int i = blockIdx.x * 256 + threadIdx.x;   // exactly N*F/8 threads
    const f32x4* p = (const f32x4*)xin + (size_t)i * 2;
    f32x4 a = __builtin_nontemporal_load(p);      // x never re-read
    f32x4 b = __builtin_nontemporal_load(p + 1);
    uint4 o;
    o.x = (unsigned)f2b(a[0]) | ((unsigned)f2b(a[1]) << 16);
    o.y = (unsigned)f2b(a[2]) | ((unsigned)f2b(a[3]) << 16);
    o.z = (unsigned)f2b(b[0]) | ((unsigned)f2b(b[1]) << 16);
    o.w = (unsigned)f2b(b[2]) | ((unsigned)f2b(b[3]) << 16);
    *(uint4*)(xb + (size_t)i * 8) = o;
}

// both weights, transposed to Wt[n][k], in one launch
__global__ void k_cvtW(const float* __restrict__ W1, const float* __restrict__ W2,
                       unsigned short* __restrict__ W1t, unsigned short* __restrict__ W2t) {
    int t = blockIdx.x * 256 + threadIdx.x;   // 2*F*F threads
    int which = t >= F * F;
    int u = t - which * F * F;
    int n = u >> 9, k = u & 511;
    const float* W = which ? W2 : W1;
    unsigned short* Wt = which ? W2t : W1t;
    Wt[u] = f2b(W[k * F + n]);
}

// ---- GEMM 256x256 2-phase dbuf: out = A[M,512] x Bt[512,512]^T + bias ----
__global__ __launch_bounds__(512, 2)
void gemm_bt(const unsigned short* __restrict__ A, const unsigned short* __restrict__ Bt,
             const float* __restrict__ bias,
             unsigned short* __restrict__ outb, float* __restrict__ outf,
             int relu, int M) {
    __shared__ unsigned short sm[65536];          // 128 KB

    // bijective XCD remap (m204): pair (bx, by=0/1) lands on one XCD
    int nwg = gridDim.x * gridDim.y;
    int orig = blockIdx.y * gridDim.x + blockIdx.x;
    int q = nwg >> 3, r = nwg & 7;
    int xcd = orig & 7, j8 = orig >> 3;
    int wgid = (xcd < r ? xcd * (q + 1) : r * (q + 1) + (xcd - r) * q) + j8;
    int by = wgid & 1;                            // N tile (0..1)
    int bx = wgid >> 1;                           // M tile

    int t  = threadIdx.x;
    int lane = t & 63, w = t >> 6;
    int wr = w >> 2, wc = w & 3;
    int rsel = lane & 15, khalf = (lane >> 4) * 8;

    f32x4 acc[8][4];
    #pragma unroll
    for (int m = 0; m < 8; ++m)
        #pragma unroll
        for (int n = 0; n < 4; ++n)
            acc[m][n] = (f32x4){0.f, 0.f, 0.f, 0.f};

    int rowBase = bx * 256;

    int ar[4], br[4], kcc[4];
    #pragma unroll
    for (int i = 0; i < 4; ++i) {
        int idx = i * 512 + t;
        int rr = idx >> 3;
        kcc[i] = (idx & 7) * 8;
        int ga = rowBase + rr; if (ga >= M) ga = M - 1;
        ar[i] = ga;
        br[i] = by * 256 + rr;
    }

    auto STAGE = [&](int buf, int k0) {
        #pragma unroll
        for (int i = 0; i < 4; ++i) {
            int idx = i * 512 + t;
            gload_lds16(A + (size_t)ar[i] * F + k0 + kcc[i], sm + buf * 16384 + idx * 8);
            gload_lds16(Bt + (size_t)br[i] * F + k0 + kcc[i], sm + 32768 + buf * 16384 + idx * 8);
        }
    };
    auto COMPUTE = [&](int buf) {
        const unsigned short* la = sm + buf * 16384;
        const unsigned short* lb = sm + 32768 + buf * 16384;
        #pragma unroll
        for (int ks = 0; ks < 2; ++ks) {
            int koff = ks * 32 + khalf;
            short8 af[8], bfr[4];
            #pragma unroll
            for (int m = 0; m < 8; ++m)
                af[m] = *(const short8*)&la[(wr * 128 + m * 16 + rsel) * 64 + koff];
            #pragma unroll
            for (int n = 0; n < 4; ++n)
                bfr[n] = *(const short8*)&lb[(wc * 64 + n * 16 + rsel) * 64 + koff];
            #pragma unroll
            for (int m = 0; m < 8; ++m)
                #pragma unroll
                for (int n = 0; n < 4; ++n)
                    acc[m][n] = __builtin_amdgcn_mfma_f32_16x16x32_bf16(af[m], bfr[n], acc[m][n], 0, 0, 0);
        }
    };

    STAGE(0, 0);
    __syncthreads();
    #pragma unroll
    for (int kp = 0; kp < 4; ++kp) {
        STAGE(1, (2 * kp + 1) * 64);
        COMPUTE(0);
        __syncthreads();
        if (kp < 3) STAGE(0, (2 * kp + 2) * 64);
        COMPUTE(1);
        __syncthreads();
    }

    int rq = (lane >> 4) * 4, cq = lane & 15;
    if (outb) {
        // stage bf16 C-tile in LDS, then coalesced 512B-row stores
        #pragma unroll
        for (int m = 0; m < 8; ++m)
            #pragma unroll
            for (int n = 0; n < 4; ++n) {
                int cl = wc * 64 + n * 16 + cq;
                float bv = bias[by * 256 + cl];
                #pragma unroll
                for (int j = 0; j < 4; ++j) {
                    int rl = wr * 128 + m * 16 + rq + j;
                    float v = acc[m][n][j] + bv;
                    if (relu) v = fmaxf(v, 0.f);
                    sm[rl * 256 + cl] = f2b(v);
                }
            }
        __syncthreads();
        #pragma unroll
        for (int p = 0; p < 16; ++p) {
            int sidx = p * 4096 + t * 8;
            int row = sidx >> 8;
            int col = sidx & 255;
            int grow = rowBase + row;
            if (grow < M) {
                uint4 v = *(const uint4*)&sm[sidx];
                *(uint4*)&outb[(size_t)grow * F + by * 256 + col] = v;
            }
        }
    } else {
        #pragma unroll
        for (int m = 0; m < 8; ++m)
            #pragma unroll
            for (int n = 0; n < 4; ++n) {
                int colv = by * 256 + wc * 64 + n * 16 + cq;
                float bv = bias[colv];
                #pragma unroll
                for (int j = 0; j < 4; ++j) {
                    int row = rowBase + wr * 128 + m * 16 + rq + j;
                    if (row < M) {
                        float v = acc[m][n][j] + bv;
                        if (relu) v = fmaxf(v, 0.f);
                        __builtin_nontemporal_store(v, outf + (size_t)row * F + colv);
                    }
                }
            }
    }
}

// ---- aggregation, source-chunked: 4 passes, each over a 25.6 MB slice of hin ----
#define LOADP(k) uint2 p##k = ev[e + k]
#define LOADV(k) uint4 v##k = *(const uint4*)(base + ((size_t)p##k.x << 9))
#define ACCV(k)  { float w_ = fbits(p##k.y); \
    acc[0] += w_ * bfu(v##k.x & 0xffffu); acc[1] += w_ * bfu(v##k.x >> 16); \
    acc[2] += w_ * bfu(v##k.y & 0xffffu); acc[3] += w_ * bfu(v##k.y >> 16); \
    acc[4] += w_ * bfu(v##k.z & 0xffffu); acc[5] += w_ * bfu(v##k.z >> 16); \
    acc[6] += w_ * bfu(v##k.w & 0xffffu); acc[7] += w_ * bfu(v##k.w >> 16); }

__global__ __launch_bounds__(256)
void k_agg(const unsigned short* __restrict__ hin, const int2* __restrict__ seg,
           const int4* __restrict__ cst, const uint2* __restrict__ ev,
           unsigned short* __restrict__ outb) {
    int node = blockIdx.x * 4 + (threadIdx.x >> 6);
    int lane = threadIdx.x & 63;
    if (node >= N_NODES) return;
    int2 se = seg[node];
    int4 cs = cst[node];
    int st[5] = {cs.x, cs.y, cs.z, cs.w, se.y};
    float acc[8] = {0, 0, 0, 0, 0, 0, 0, 0};
    const unsigned short* base = hin + lane * 8;

    #pragma unroll
    for (int c = 0; c < NCHUNK; ++c) {
        int e = st[c], end = st[c + 1];
        for (; e + 3 < end; e += 4) {
            LOADP(0); LOADP(1); LOADP(2); LOADP(3);
            LOADV(0); LOADV(1); LOADV(2); LOADV(3);
            ACCV(0); ACCV(1); ACCV(2); ACCV(3);
        }
        for (; e < end; ++e) {
            LOADP(0); LOADV(0); ACCV(0);
        }
    }

    uint4 o;
    o.x = (unsigned)f2b(acc[0]) | ((unsigned)f2b(acc[1]) << 16);
    o.y = (unsigned)f2b(acc[2]) | ((unsigned)f2b(acc[3]) << 16);
    o.z = (unsigned)f2b(acc[4]) | ((unsigned)f2b(acc[5]) << 16);
    o.w = (unsigned)f2b(acc[6]) | ((unsigned)f2b(acc[7]) << 16);
    *(uint4*)(outb + (size_t)node * F + lane * 8) = o;
}

extern "C" void kernel_launch(void* const* d_in, const int* in_sizes, int n_in,
                              void* d_out, int out_size, void* d_ws, size_t ws_size,
                              hipStream_t stream) {
    const float* x  = (const float*)d_in[0];
    const int*   ei = (const int*)d_in[1];
    const float* W1 = (const float*)d_in[2];
    const float* b1 = (const float*)d_in[3];
    const float* W2 = (const float*)d_in[4];
    const float* b2 = (const float*)d_in[5];
    float* out = (float*)d_out;

    char* ws = (char*)d_ws;
    size_t off = 0;
    auto alloc = [&](size_t bytes) -> void* {
        off = (off + 255) & ~(size_t)255;
        void* p = ws + off;
        off += bytes;
        return p;
    };

    unsigned short* tb   = (unsigned short*)alloc((size_t)N_NODES * F * 2); // agg out (bf16)
    unsigned short* W1t  = (unsigned short*)alloc((size_t)F * F * 2);
    unsigned short* W2t  = (unsigned short*)alloc((size_t)F * F * 2);
    uint4*          deg4 = (uint4*)alloc((size_t)N_NODES * 16);  // degrees, then cursors
    float*          dis  = (float*)alloc((size_t)N_NODES * 4);
    int2*           seg  = (int2*)alloc((size_t)N_NODES * 8);
    int4*           cst  = (int4*)alloc((size_t)N_NODES * 16);
    unsigned int*   cnt  = (unsigned int*)alloc(256);
    uint2*          ev   = (uint2*)alloc((size_t)E_TOT * 8);

    // d_out doubles as scratch: lower half = h1 (bf16), upper half = x (bf16).
    unsigned short* h1b = (unsigned short*)d_out;
    unsigned short* xb  = (unsigned short*)((char*)d_out + (size_t)N_NODES * F * 2);

    int nb = (N_NODES + 255) / 256;

    k_init<<<nb, 256, 0, stream>>>(deg4, cnt);
    k_hist<<<(E_EDGES + 255) / 256, 256, 0, stream>>>(ei, (unsigned int*)deg4);
    k_disalloc<<<nb, 256, 0, stream>>>(deg4, cnt, dis, seg, cst);
    k_scatter<<<(E_TOT + 255) / 256, 256, 0, stream>>>(ei, dis, (unsigned int*)deg4, ev);

    k_cvtW<<<(2 * F * F) / 256, 256, 0, stream>>>(W1, W2, W1t, W2t);
    k_cvtX<<<(N_NODES * F / 8) / 256, 256, 0, stream>>>(x, xb);

    dim3 ggrid(2, (N_NODES + 255) / 256);

    // layer 1: h1 = relu((A x) W1 + b1)   [reassociated]
    k_agg<<<(N_NODES + 3) / 4, 256, 0, stream>>>(xb, seg, cst, ev, tb);
    gemm_bt<<<ggrid, 512, 0, stream>>>(tb, W1t, b1, h1b, nullptr, 1, N_NODES);

    // layer 2: out = (A h1) W2 + b2       [reassociated]
    k_agg<<<(N_NODES + 3) / 4, 256, 0, stream>>>(h1b, seg, cst, ev, tb);
    gemm_bt<<<ggrid, 512, 0, stream>>>(tb, W2t, b2, nullptr, out, 0, N_NODES);
}